// Round 7
// baseline (778.478 us; speedup 1.0000x reference)
//
#include <hip/hip_runtime.h>

#define DI __device__ __forceinline__

typedef __attribute__((ext_vector_type(8))) short short8;   // 8 bf16 (round-4-verified MFMA frag type)
typedef __attribute__((ext_vector_type(4))) float f32x4;

static constexpr int Bb  = 32;
static constexpr int Tt  = 12;
static constexpr int FIN = 16;
static constexpr int NN  = 2048;
static constexpr int HID = 3;
static constexpr int M1  = Bb*Tt*FIN;    // 6144
static constexpr int M2  = Bb*Tt*32;     // 12288

DI float b2f(unsigned short u){
  unsigned int v = ((unsigned int)u) << 16;
  float f; __builtin_memcpy(&f, &v, 4); return f;
}
DI unsigned short f2b(float f){
  unsigned int v; __builtin_memcpy(&v, &f, 4);
  v = v + 0x7FFFu + ((v >> 16) & 1u);
  return (unsigned short)(v >> 16);
}
DI float ld(const void* p, size_t i, int flag){
  return flag ? b2f(((const unsigned short*)p)[i]) : ((const float*)p)[i];
}

// async global->LDS, 16B per lane. LDS dest must be wave-uniform base + lane*16 (it is:
// dest offsets are tid-linear). Global src is per-lane (carries the XOR swizzle).
typedef __attribute__((address_space(1))) const unsigned int g_u32;
typedef __attribute__((address_space(3))) unsigned int l_u32;
DI void gll16(const unsigned short* g, unsigned short* l){
  __builtin_amdgcn_global_load_lds((g_u32*)g, (l_u32*)l, 16, 0, 0);
}

// ---------------- dtype sniff (+ zero att0 accumulators) ----------------
__global__ void k_sniff(const unsigned short* __restrict__ x, int* __restrict__ flag,
                        float* __restrict__ att0){
  int tid = threadIdx.x;
  for (int j = tid; j < Bb*Tt; j += 64) att0[j] = 0.f;
  float v = b2f(x[tid*2]);
  int bad = (!(v == v)) || (fabsf(v) > 1e6f);
  unsigned long long m = __ballot(bad);
  if (tid == 0) *flag = (m == 0ull) ? 1 : 0;
}

// ---------------- convert to guaranteed-bf16 (src element offset `off`) ----------------
// If att0 != nullptr (x-convert): also accumulate per-(b,t) sums for the SE attention
// mean (fuses k_att_mean — saves a full 50 MB re-read of x). Each block's 2048 elems
// lie within one (b,t) chunk (32768 elems), so one atomicAdd per block.
__global__ void k_convert(const void* __restrict__ src, unsigned short* __restrict__ dst,
                          long long n8, const int* __restrict__ flagp, long long off,
                          float* __restrict__ att0){
  int flag = *flagp;
  int tid = threadIdx.x;
  long long i = (long long)blockIdx.x*256 + tid;
  float s = 0.f;
  if (i < n8){
    size_t base = (size_t)i * 8;
    if (flag){
      uint4 u = *(const uint4*)((const unsigned short*)src + off + base);
      *(uint4*)(dst + base) = u;
      if (att0){
        unsigned short sp[8]; __builtin_memcpy(sp, &u, 16);
        #pragma unroll
        for (int j = 0; j < 8; ++j) s += b2f(sp[j]);
      }
    } else {
      const float* f = (const float*)src + off + base;
      unsigned short o[8];
      #pragma unroll
      for (int j = 0; j < 8; ++j){ float fv = f[j]; o[j] = f2b(fv); s += fv; }
      uint4 ov; __builtin_memcpy(&ov, o, 16);
      *(uint4*)(dst + base) = ov;
    }
  }
  if (att0){
    for (int o2 = 32; o2; o2 >>= 1) s += __shfl_down(s, o2);
    __shared__ float red[4];
    if ((tid & 63) == 0) red[tid >> 6] = s;
    __syncthreads();
    if (tid == 0){
      int bt = (int)(blockIdx.x >> 4);   // 2048 elems/block, 32768 elems per (b,t)
      atomicAdd(&att0[bt], red[0] + red[1] + red[2] + red[3]);
    }
  }
}

// ---------------- SE attention MLP (att0 holds raw sums; scale by 1/(F*N) here) ----------------
__global__ void k_att_mlp(const float* __restrict__ att0,
                          const void* __restrict__ m1w, const void* __restrict__ m1b,
                          const void* __restrict__ m2w, const void* __restrict__ m2b,
                          float* __restrict__ att, const int* __restrict__ flagp){
  int flag = *flagp;
  int b = threadIdx.x;
  if (b >= Bb) return;
  float a[Tt];
  #pragma unroll
  for (int t = 0; t < Tt; ++t) a[t] = att0[b*Tt + t] * (1.f / (FIN*NN));
  float h[HID];
  #pragma unroll
  for (int j = 0; j < HID; ++j){
    float s = ld(m1b, j, flag);
    #pragma unroll
    for (int t = 0; t < Tt; ++t) s += a[t] * ld(m1w, j*Tt + t, flag);
    h[j] = s > 0.f ? s : 0.f;
  }
  #pragma unroll
  for (int t = 0; t < Tt; ++t){
    float s = ld(m2b, t, flag);
    #pragma unroll
    for (int j = 0; j < HID; ++j) s += h[j] * ld(m2w, t*HID + j, flag);
    att[b*Tt + t] = 1.f / (1.f + expf(-s));
  }
}

// ---------------- fused gconv main-loop helpers ----------------
// stage one BK=32 K-strip of A[128][32] + B[2][128][32] into LDS buffer (async, swizzled src).
// EXACTLY 6 global_load_lds per thread (2 A + 4 B) — vmcnt accounting depends on it.
DI void stage_tile(const unsigned short* __restrict__ Ag,
                   const unsigned short* __restrict__ chb,
                   unsigned short* Ad, unsigned short* Bd,
                   int row0, int gn0, int kk0, int tid){
  #pragma unroll
  for (int p = 0; p < 2; ++p){
    int s = tid + p*256, r = s >> 2, j = s & 3;       // A: 128 rows x 4 blocks of 8 bf16
    gll16(Ag + (size_t)(row0 + r)*NN + kk0 + ((j ^ (r & 3)) << 3), Ad + (s << 3));
  }
  #pragma unroll
  for (int p = 0; p < 4; ++p){
    int s = tid + p*256, k = s >> 9, rem = s & 511, r = rem >> 2, j = rem & 3;  // B: 2 planes
    gll16(chb + (size_t)k*NN*NN + (size_t)(gn0 + r)*NN + kk0 + ((j ^ (r & 3)) << 3), Bd + (s << 3));
  }
}

// consume one staged BK=32 strip: 12 ds_read_b128 + 32 MFMA
DI void compute_tile(const unsigned short* As, const unsigned short* Bs,
                     f32x4 (&acc)[2][8][2], int w, int cc, int q){
  short8 af[8];
  #pragma unroll
  for (int mt = 0; mt < 8; ++mt)
    af[mt] = *(const short8*)(As + ((mt*16 + cc) << 5) + ((q ^ (cc & 3)) << 3));
  #pragma unroll
  for (int k = 0; k < 2; ++k){
    #pragma unroll
    for (int ns = 0; ns < 2; ++ns){
      int r = w*32 + ns*16 + cc;       // (r&3) == (cc&3)
      short8 bv = *(const short8*)(Bs + (((k << 7) + r) << 5) + ((q ^ (cc & 3)) << 3));
      #pragma unroll
      for (int mt = 0; mt < 8; ++mt)
        acc[k][mt][ns] = __builtin_amdgcn_mfma_f32_16x16x32_bf16(af[mt], bv, acc[k][mt][ns], 0, 0, 0);
    }
  }
}

// counted-vmcnt wait + single barrier per K-step (m218 pattern, 1 barrier — round-3's
// failure was the SECOND per-step barrier). N=6: with a 3-buffer ring, at the wait point
// exactly 2 stages (12 loads) are outstanding; waiting to 6 drains only the OLDEST stage.
DI void wait_bar_6(){
  asm volatile("s_waitcnt vmcnt(6)" ::: "memory");
  __builtin_amdgcn_s_barrier();
  asm volatile("" ::: "memory");
}
DI void wait_bar_0(){
  asm volatile("s_waitcnt vmcnt(0)" ::: "memory");
  __builtin_amdgcn_s_barrier();
  asm volatile("" ::: "memory");
}

// ---------------- fused gconv: X[bt*32+o][n] = relu( sum_{kk} theta_T[o][kk] * zfull[kk][n] )
// zfull rows: [0,F) identity (A, att-scaled if SCALE), [F,2F) A@cheb1^T, [2F,3F) A@cheb2^T.
// Main loop: 128x128 tile MFMA GEMM over 2 cheb planes, BK=32, THREE-buffer LDS ring,
// depth-2 prefetch via global_load_lds (16B), counted vmcnt(6), ONE barrier per K-step,
// stage issued AFTER the barrier (write target = buffer read at step i-1, read-complete
// by construction: each wave's ds_reads are consumed by its MFMAs before the barrier).
// Round-2 XCD remap (FETCH 2.6x) and round-4 occupancy raise (acc spill) stay reverted.
// att scale applied entirely in the epilogue (row-scale commutes with the graph mix).
template <int SCALE, int F>
__global__ __launch_bounds__(256, 2)
void k_gemm(const unsigned short* __restrict__ Ag,
            const float* __restrict__ att,
            const unsigned short* __restrict__ chb,   // planes 1,2 only: [2][NN][NN]
            const void* __restrict__ theta,           // [3][F][32], dtype per flag
            unsigned short* __restrict__ X,           // out [bt*32+o][NN] bf16
            const int* __restrict__ flagp){
  constexpr int Kp = (F == 16) ? 64 : 96;     // zero-padded K for the mix MFMA
  constexpr int PP = (F == 16) ? 72 : 104;    // LDS pitch (16B-multiple, bank-spread)
  constexpr int G  = 128 / F;                 // bt-groups per 128-row tile
  constexpr int NKB = Kp / 32;
  constexpr int BUF = 128*32 + 2*128*32;      // 12288 halves per buffer (A | B)

  __shared__ __align__(16) unsigned short SMEM[3*BUF];     // 72 KB ring, reused as zs
  __shared__ __align__(16) unsigned short TT[32*PP];       // theta^T bf16 [o][kk]

  int flag = *flagp;
  int tid  = threadIdx.x;
  int w    = tid >> 6, lane = tid & 63, q = lane >> 4, cc = lane & 15;
  int row0 = blockIdx.x * 128;
  int gn0  = blockIdx.y * 128;

  // stage theta^T (zero-padded); consumed only in the epilogue (after __syncthreads)
  for (int idx = tid; idx < 32*PP; idx += 256){
    int o = idx / PP, kk = idx % PP;
    float v = (kk < 3*F) ? ld(theta, (size_t)kk*32 + o, flag) : 0.f;
    TT[idx] = f2b(v);
  }

  f32x4 zero4 = {0.f, 0.f, 0.f, 0.f};
  f32x4 acc[2][8][2];
  #pragma unroll
  for (int k = 0; k < 2; ++k)
    #pragma unroll
    for (int mt = 0; mt < 8; ++mt)
      #pragma unroll
      for (int ns = 0; ns < 2; ++ns) acc[k][mt][ns] = zero4;

  // ring pointers (named, swap-rotated — no dynamic indexing, rule #20)
  unsigned short *Ac = SMEM,           *Bc = SMEM + 4096;
  unsigned short *An = SMEM +   BUF,   *Bn = SMEM +   BUF + 4096;
  unsigned short *Af = SMEM + 2*BUF,   *Bf = SMEM + 2*BUF + 4096;

  // prologue: 2 stages in flight (12 loads/wave)
  stage_tile(Ag, chb, Ac, Bc, row0, gn0, 0,  tid);
  stage_tile(Ag, chb, An, Bn, row0, gn0, 32, tid);

  // steady state: wait oldest stage only, barrier, issue stage(it+2), compute(it)
  for (int it = 0; it < 63; ++it){
    wait_bar_6();
    if (it < 62) stage_tile(Ag, chb, Af, Bf, row0, gn0, (it + 2) * 32, tid);
    compute_tile(Ac, Bc, acc, w, cc, q);
    unsigned short* tA = Ac; Ac = An; An = Af; Af = tA;
    unsigned short* tB = Bc; Bc = Bn; Bn = Bf; Bf = tB;
  }
  wait_bar_0();
  compute_tile(Ac, Bc, acc, w, cc, q);

  __syncthreads();   // full drain: main-loop LDS reads done; SMEM free for reuse; TT visible

  // ---- epilogue: wave-private z repack + theta^T MFMA mix ----
  unsigned short* zs = SMEM + w * (32*PP);   // [32 cols][PP]

  short8 afm[2][NKB];
  #pragma unroll
  for (int mt_o = 0; mt_o < 2; ++mt_o)
    #pragma unroll
    for (int kb = 0; kb < NKB; ++kb)
      afm[mt_o][kb] = *(const short8*)(TT + (mt_o*16 + cc)*PP + kb*32 + q*8);

  if (F == 16){                              // zero rows [48,64) once
    if (lane < 32){
      #pragma unroll
      for (int j = 0; j < 4; ++j) *(uint2*)(zs + lane*PP + 48 + j*4) = make_uint2(0u, 0u);
    }
  }

  int bt0 = row0 / F;
  #pragma unroll
  for (int g = 0; g < G; ++g){
    float sc = SCALE ? att[bt0 + g] : 1.f;
    // identity rows [0,F): zs[col][f] = Ag[row0+g*F+f][gn0 + w*32 + col] (scaled)
    #pragma unroll
    for (int pass = 0; pass < F/16; ++pass){
      int rf = pass*16 + (lane >> 2), c8 = (lane & 3) * 8;
      uint4 u = *(const uint4*)(Ag + (size_t)(row0 + g*F + rf)*NN + gn0 + w*32 + c8);
      unsigned short sp[8]; __builtin_memcpy(sp, &u, 16);
      #pragma unroll
      for (int e = 0; e < 8; ++e){
        unsigned short val = SCALE ? f2b(b2f(sp[e]) * sc) : sp[e];
        zs[(c8 + e)*PP + rf] = val;
      }
    }
    // plane rows [F,3F) from acc (att scale applied here — commutes with graph mix)
    #pragma unroll
    for (int k = 0; k < 2; ++k)
      #pragma unroll
      for (int mt_l = 0; mt_l < F/16; ++mt_l)
        #pragma unroll
        for (int ns = 0; ns < 2; ++ns){
          int mt = g*(F/16) + mt_l;
          f32x4 v = acc[k][mt][ns];
          #pragma unroll
          for (int r = 0; r < 4; ++r){
            float pv = SCALE ? v[r] * sc : v[r];
            zs[(ns*16 + cc)*PP + F*(k+1) + mt_l*16 + q*4 + r] = f2b(pv);
          }
        }
    // mix MFMA: out[o][col] = sum_kk TT[o][kk] * zs[col][kk]
    #pragma unroll
    for (int mt_o = 0; mt_o < 2; ++mt_o)
      #pragma unroll
      for (int ch = 0; ch < 2; ++ch){
        f32x4 am = zero4;
        #pragma unroll
        for (int kb = 0; kb < NKB; ++kb){
          short8 bm = *(const short8*)(zs + (ch*16 + cc)*PP + kb*32 + q*8);
          am = __builtin_amdgcn_mfma_f32_16x16x32_bf16(afm[mt_o][kb], bm, am, 0, 0, 0);
        }
        #pragma unroll
        for (int r = 0; r < 4; ++r){
          int o = mt_o*16 + q*4 + r;
          float v = am[r]; v = v > 0.f ? v : 0.f;
          X[((size_t)((bt0 + g)*32 + o))*NN + gn0 + w*32 + ch*16 + cc] = f2b(v);
        }
      }
  }
}

// ---------------- temporal conv 1 (kernel (1,2), wrap-pad, relu) ----------------
__global__ void k_tconv1(const unsigned short* __restrict__ xin,
                         const void* __restrict__ wgt, const void* __restrict__ bias,
                         unsigned short* __restrict__ yout, const int* __restrict__ flagp){
  int flag = *flagp;
  __shared__ float wl[32*32*2];
  __shared__ float bl[32];
  int tid = threadIdx.x;
  for (int i = tid; i < 2048; i += 256) wl[i] = ld(wgt, i, flag);
  if (tid < 32) bl[tid] = ld(bias, tid, flag);
  __syncthreads();
  int bt = blockIdx.x, b = bt / 12, t = bt % 12;
  int c = (t == 0) ? 10 : (t - 1);
  int n = blockIdx.y*256 + tid;
  const unsigned short* p0 = xin + ((size_t)(b*12 + c  )*32)*NN + n;
  const unsigned short* p1 = xin + ((size_t)(b*12 + c+1)*32)*NN + n;
  float acc[32];
  #pragma unroll
  for (int o = 0; o < 32; ++o) acc[o] = bl[o];
  for (int i = 0; i < 32; ++i){
    float v0 = b2f(p0[(size_t)i*NN]);
    float v1 = b2f(p1[(size_t)i*NN]);
    #pragma unroll
    for (int o = 0; o < 32; ++o) acc[o] += v0*wl[o*64 + i*2] + v1*wl[o*64 + i*2 + 1];
  }
  unsigned short* op = yout + ((size_t)bt*32)*NN + n;
  #pragma unroll
  for (int o = 0; o < 32; ++o){ float v = acc[o]; op[(size_t)o*NN] = f2b(v > 0.f ? v : 0.f); }
}

// ---------------- tconv2 + relu + residual + LayerNorm + relu ----------------
// og=2 (16 out-channels per block): halves the redundant re-read of the yp/x slices.
// SPILL DISCIPLINE (rounds 4+5 lesson): acc[16][8] = 128 f32/thread REQUIRES
// __launch_bounds__(256,2); weight reads are scalar LDS broadcasts (wave-uniform).
__global__ __launch_bounds__(256, 2)
void k_tail(const unsigned short* __restrict__ yp,
            const void* __restrict__ x,
            const void* __restrict__ w2, const void* __restrict__ b2v,
            const void* __restrict__ rw, const void* __restrict__ rbv,
            const void* __restrict__ lng, const void* __restrict__ lnb,
            void* __restrict__ out, const int* __restrict__ flagp){
  int flag = *flagp;
  __shared__ float wt0[32*16], wt1[32*16];   // [i][oo] taps, transposed
  __shared__ float rt[16*16];                // [i][oo] residual 1x1, transposed
  __shared__ float bcv[16], rbc[16];
  __shared__ float redS[4*16], redS2[4*16];
  int tid = threadIdx.x;
  int bt = blockIdx.x, og = blockIdx.y, o0 = og*16;
  int b = bt / 12, t = bt % 12, c = (t == 0) ? 10 : (t - 1);
  for (int idx = tid; idx < 512; idx += 256){
    int i = idx >> 4, oo = idx & 15;
    wt0[idx] = ld(w2, (size_t)(o0 + oo)*64 + i*2,     flag);
    wt1[idx] = ld(w2, (size_t)(o0 + oo)*64 + i*2 + 1, flag);
  }
  if (tid < 256){
    int i = tid >> 4, oo = tid & 15;
    rt[tid] = ld(rw, (size_t)(o0 + oo)*16 + i, flag);
  }
  if (tid < 16){ bcv[tid] = ld(b2v, o0 + tid, flag); rbc[tid] = ld(rbv, o0 + tid, flag); }
  __syncthreads();
  float acc[16][8];
  #pragma unroll
  for (int oo = 0; oo < 16; ++oo)
    #pragma unroll
    for (int nn = 0; nn < 8; ++nn) acc[oo][nn] = bcv[oo];
  const unsigned short* p0 = yp + ((size_t)(b*12 + c  )*32)*NN;
  const unsigned short* p1 = yp + ((size_t)(b*12 + c+1)*32)*NN;
  for (int i = 0; i < 32; ++i){
    float v0[8], v1[8];
    #pragma unroll
    for (int nn = 0; nn < 8; ++nn){
      int n = nn*256 + tid;
      v0[nn] = b2f(p0[(size_t)i*NN + n]);
      v1[nn] = b2f(p1[(size_t)i*NN + n]);
    }
    #pragma unroll
    for (int oo = 0; oo < 16; ++oo){
      float w0 = wt0[i*16 + oo];
      float w1 = wt1[i*16 + oo];
      #pragma unroll
      for (int nn = 0; nn < 8; ++nn) acc[oo][nn] += v0[nn]*w0 + v1[nn]*w1;
    }
  }
  #pragma unroll
  for (int oo = 0; oo < 16; ++oo)
    #pragma unroll
    for (int nn = 0; nn < 8; ++nn){ float v = acc[oo][nn]; acc[oo][nn] = (v > 0.f ? v : 0.f) + rbc[oo]; }
  size_t xbase = ((size_t)(b*12 + t)*16)*NN;
  for (int i = 0; i < 16; ++i){
    float xv[8];
    #pragma unroll
    for (int nn = 0; nn < 8; ++nn) xv[nn] = ld(x, xbase + (size_t)i*NN + nn*256 + tid, flag);
    #pragma unroll
    for (int oo = 0; oo < 16; ++oo){
      float r = rt[i*16 + oo];
      #pragma unroll
      for (int nn = 0; nn < 8; ++nn) acc[oo][nn] += xv[nn]*r;
    }
  }
  int lane = tid & 63, wv = tid >> 6;
  #pragma unroll
  for (int oo = 0; oo < 16; ++oo){
    float s = 0.f, s2 = 0.f;
    #pragma unroll
    for (int nn = 0; nn < 8; ++nn){ float v = acc[oo][nn]; s += v; s2 += v*v; }
    for (int off = 32; off; off >>= 1){ s += __shfl_down(s, off); s2 += __shfl_down(s2, off); }
    if (lane == 0){ redS[wv*16 + oo] = s; redS2[wv*16 + oo] = s2; }
  }
  __syncthreads();
  size_t obase = ((size_t)((b*12 + t)*32 + o0))*NN;
  #pragma unroll
  for (int nn = 0; nn < 8; ++nn){
    int n = nn*256 + tid;
    float g = ld(lng, n, flag), be = ld(lnb, n, flag);
    #pragma unroll
    for (int oo = 0; oo < 16; ++oo){
      float S  = redS [oo] + redS [16 + oo] + redS [32 + oo] + redS [48 + oo];
      float S2 = redS2[oo] + redS2[16 + oo] + redS2[32 + oo] + redS2[48 + oo];
      float m = S * (1.f/2048.f);
      float var = S2 * (1.f/2048.f) - m*m;
      float inv = rsqrtf(var + 1e-5f);
      float v = (acc[oo][nn] - m)*inv*g + be;
      v = v > 0.f ? v : 0.f;
      if (flag) ((unsigned short*)out)[obase + (size_t)oo*NN + n] = f2b(v);
      else      ((float*)out)[obase + (size_t)oo*NN + n] = v;
    }
  }
}

// ---------------- launcher ----------------
extern "C" void kernel_launch(void* const* d_in, const int* in_sizes, int n_in,
                              void* d_out, int out_size, void* d_ws, size_t ws_size,
                              hipStream_t stream){
  const void* x    = d_in[0];
  const void* cheb = d_in[1];
  const void* th1  = d_in[2];
  const void* th2  = d_in[3];
  const void* m1w  = d_in[4];
  const void* m1b  = d_in[5];
  const void* m2w  = d_in[6];
  const void* m2b  = d_in[7];
  const void* t1w  = d_in[8];
  const void* t1b  = d_in[9];
  const void* t2w  = d_in[10];
  const void* t2b  = d_in[11];
  const void* rw   = d_in[12];
  const void* rb   = d_in[13];
  const void* lng  = d_in[14];
  const void* lnb  = d_in[15];
  char* ws = (char*)d_ws;

  int*   flag  = (int*)ws;
  float* att0  = (float*)(ws + 4096);
  float* att   = (float*)(ws + 8192);
  unsigned short* xb  = (unsigned short*)(ws + 16384);        // x bf16: 25.2 MB
  unsigned short* chb = xb + (size_t)M1*NN;                   // cheb planes 1,2 bf16: 16.8 MB
  unsigned short* X1  = chb + (size_t)2*NN*NN;                // gconv1 out: 50.3 MB
  unsigned short* X2  = (unsigned short*)d_out;               // gconv2 out (bf16 scratch in d_out)
  unsigned short* Y1  = X1;                                   // tconv1 out reuses X1

  k_sniff  <<<1, 64, 0, stream>>>((const unsigned short*)x, flag, att0);
  k_convert<<<((long long)M1*NN/8 + 255)/256, 256, 0, stream>>>(x, xb, (long long)M1*NN/8, flag, 0, att0);
  k_convert<<<((long long)2*NN*NN/8 + 255)/256, 256, 0, stream>>>(cheb, chb, (long long)2*NN*NN/8, flag, (long long)NN*NN, nullptr);
  k_att_mlp <<<1, 64, 0, stream>>>(att0, m1w, m1b, m2w, m2b, att, flag);

  k_gemm<1,16><<<dim3(M1/128, 16), 256, 0, stream>>>(xb, att, chb, th1, X1, flag);
  k_gemm<0,32><<<dim3(M2/128, 16), 256, 0, stream>>>(X1, att, chb, th2, X2, flag);

  k_tconv1<<<dim3(384, 8), 256, 0, stream>>>(X2, t1w, t1b, Y1, flag);
  k_tail  <<<dim3(384, 2), 256, 0, stream>>>(Y1, x, t2w, t2b, rw, rb, lng, lnb, d_out, flag);
}

// Round 8
// 741.978 us; speedup vs baseline: 1.0492x; 1.0492x over previous
//
#include <hip/hip_runtime.h>

#define DI __device__ __forceinline__

typedef __attribute__((ext_vector_type(8))) short short8;   // 8 bf16 (round-4-verified MFMA frag type)
typedef __attribute__((ext_vector_type(4))) float f32x4;

static constexpr int Bb  = 32;
static constexpr int Tt  = 12;
static constexpr int FIN = 16;
static constexpr int NN  = 2048;
static constexpr int HID = 3;
static constexpr int M1  = Bb*Tt*FIN;    // 6144
static constexpr int M2  = Bb*Tt*32;     // 12288

DI float b2f(unsigned short u){
  unsigned int v = ((unsigned int)u) << 16;
  float f; __builtin_memcpy(&f, &v, 4); return f;
}
DI unsigned short f2b(float f){
  unsigned int v; __builtin_memcpy(&v, &f, 4);
  v = v + 0x7FFFu + ((v >> 16) & 1u);
  return (unsigned short)(v >> 16);
}
DI float ld(const void* p, size_t i, int flag){
  return flag ? b2f(((const unsigned short*)p)[i]) : ((const float*)p)[i];
}

// async global->LDS, 16B per lane. LDS dest must be wave-uniform base + lane*16 (it is:
// dest offsets are tid-linear). Global src is per-lane (carries the XOR swizzle).
typedef __attribute__((address_space(1))) const unsigned int g_u32;
typedef __attribute__((address_space(3))) unsigned int l_u32;
DI void gll16(const unsigned short* g, unsigned short* l){
  __builtin_amdgcn_global_load_lds((g_u32*)g, (l_u32*)l, 16, 0, 0);
}

// ---------------- dtype sniff (+ zero att0 accumulators) ----------------
__global__ void k_sniff(const unsigned short* __restrict__ x, int* __restrict__ flag,
                        float* __restrict__ att0){
  int tid = threadIdx.x;
  for (int j = tid; j < Bb*Tt; j += 64) att0[j] = 0.f;
  float v = b2f(x[tid*2]);
  int bad = (!(v == v)) || (fabsf(v) > 1e6f);
  unsigned long long m = __ballot(bad);
  if (tid == 0) *flag = (m == 0ull) ? 1 : 0;
}

// ---------------- convert to guaranteed-bf16 (src element offset `off`) ----------------
// If att0 != nullptr (x-convert): also accumulate per-(b,t) sums for the SE attention
// mean (fuses k_att_mean — saves a full 50 MB re-read of x). Each block's 2048 elems
// lie within one (b,t) chunk (32768 elems), so one atomicAdd per block.
__global__ void k_convert(const void* __restrict__ src, unsigned short* __restrict__ dst,
                          long long n8, const int* __restrict__ flagp, long long off,
                          float* __restrict__ att0){
  int flag = *flagp;
  int tid = threadIdx.x;
  long long i = (long long)blockIdx.x*256 + tid;
  float s = 0.f;
  if (i < n8){
    size_t base = (size_t)i * 8;
    if (flag){
      uint4 u = *(const uint4*)((const unsigned short*)src + off + base);
      *(uint4*)(dst + base) = u;
      if (att0){
        unsigned short sp[8]; __builtin_memcpy(sp, &u, 16);
        #pragma unroll
        for (int j = 0; j < 8; ++j) s += b2f(sp[j]);
      }
    } else {
      const float* f = (const float*)src + off + base;
      unsigned short o[8];
      #pragma unroll
      for (int j = 0; j < 8; ++j){ float fv = f[j]; o[j] = f2b(fv); s += fv; }
      uint4 ov; __builtin_memcpy(&ov, o, 16);
      *(uint4*)(dst + base) = ov;
    }
  }
  if (att0){
    for (int o2 = 32; o2; o2 >>= 1) s += __shfl_down(s, o2);
    __shared__ float red[4];
    if ((tid & 63) == 0) red[tid >> 6] = s;
    __syncthreads();
    if (tid == 0){
      int bt = (int)(blockIdx.x >> 4);   // 2048 elems/block, 32768 elems per (b,t)
      atomicAdd(&att0[bt], red[0] + red[1] + red[2] + red[3]);
    }
  }
}

// ---------------- SE attention MLP (att0 holds raw sums; scale by 1/(F*N) here) ----------------
__global__ void k_att_mlp(const float* __restrict__ att0,
                          const void* __restrict__ m1w, const void* __restrict__ m1b,
                          const void* __restrict__ m2w, const void* __restrict__ m2b,
                          float* __restrict__ att, const int* __restrict__ flagp){
  int flag = *flagp;
  int b = threadIdx.x;
  if (b >= Bb) return;
  float a[Tt];
  #pragma unroll
  for (int t = 0; t < Tt; ++t) a[t] = att0[b*Tt + t] * (1.f / (FIN*NN));
  float h[HID];
  #pragma unroll
  for (int j = 0; j < HID; ++j){
    float s = ld(m1b, j, flag);
    #pragma unroll
    for (int t = 0; t < Tt; ++t) s += a[t] * ld(m1w, j*Tt + t, flag);
    h[j] = s > 0.f ? s : 0.f;
  }
  #pragma unroll
  for (int t = 0; t < Tt; ++t){
    float s = ld(m2b, t, flag);
    #pragma unroll
    for (int j = 0; j < HID; ++j) s += h[j] * ld(m2w, t*HID + j, flag);
    att[b*Tt + t] = 1.f / (1.f + expf(-s));
  }
}

// ---------------- fused gconv main-loop helpers ----------------
// stage one BK=32 K-strip of A[MTILE][32] + B[2][128][32] into LDS buffer (async,
// swizzled src). Guard for MTILE<128 is safe: sync is via __syncthreads (full drain),
// not counted vmcnt, so thread-varying load counts are fine.
template <int MTILE>
DI void stage_tile(const unsigned short* __restrict__ Ag,
                   const unsigned short* __restrict__ chb,
                   unsigned short* Ad, unsigned short* Bd,
                   int row0, int gn0, int kk0, int tid){
  #pragma unroll
  for (int p = 0; p < 2; ++p){
    int s = tid + p*256;
    if (s < MTILE*4){
      int r = s >> 2, j = s & 3;       // A: MTILE rows x 4 blocks of 8 bf16
      gll16(Ag + (size_t)(row0 + r)*NN + kk0 + ((j ^ (r & 3)) << 3), Ad + (s << 3));
    }
  }
  #pragma unroll
  for (int p = 0; p < 4; ++p){
    int s = tid + p*256, k = s >> 9, rem = s & 511, r = rem >> 2, j = rem & 3;  // B: 2 planes
    gll16(chb + (size_t)k*NN*NN + (size_t)(gn0 + r)*NN + kk0 + ((j ^ (r & 3)) << 3), Bd + (s << 3));
  }
}

// consume one staged BK=32 strip: (MT+4) ds_read_b128 + 4*MT MFMA
template <int MT>
DI void compute_tile(const unsigned short* As, const unsigned short* Bs,
                     f32x4 (&acc)[2][MT][2], int w, int cc, int q){
  short8 af[MT];
  #pragma unroll
  for (int mt = 0; mt < MT; ++mt)
    af[mt] = *(const short8*)(As + ((mt*16 + cc) << 5) + ((q ^ (cc & 3)) << 3));
  #pragma unroll
  for (int k = 0; k < 2; ++k){
    #pragma unroll
    for (int ns = 0; ns < 2; ++ns){
      int r = w*32 + ns*16 + cc;       // (r&3) == (cc&3)
      short8 bv = *(const short8*)(Bs + (((k << 7) + r) << 5) + ((q ^ (cc & 3)) << 3));
      #pragma unroll
      for (int mt = 0; mt < MT; ++mt)
        acc[k][mt][ns] = __builtin_amdgcn_mfma_f32_16x16x32_bf16(af[mt], bv, acc[k][mt][ns], 0, 0, 0);
    }
  }
}

// ---------------- fused gconv body: X[bt*32+o][n] = relu( sum_kk theta_T[o][kk]*z[kk][n] )
// zfull rows: [0,F) identity (A, att-scaled if SCALE), [F,2F) A@cheb1^T, [2F,3F) A@cheb2^T.
// Main loop: MTILE x 128 tile MFMA GEMM over 2 cheb planes, BK=32, LDS double-buffered,
// staged via global_load_lds (16B), next-tile prefetch issued before compute.
// PIPELINE VERDICT (rounds 2,3,7): counted-vmcnt rings (2-barrier AND 1-barrier) are
// null-to-negative on this 2-phase structure; the plain __syncthreads dbuf IS the m97
// ceiling (873 TF measured for gconv2). Round-2 XCD remap (FETCH 2.6x) and round-4/5
// occupancy raises (acc spill) also reverted. 2 blocks/CU is register-mandated.
template <int SCALE, int F, int MTILE>
DI void gemm_body(const unsigned short* __restrict__ Ag,
                  const float* __restrict__ att,
                  const unsigned short* __restrict__ chb,   // planes 1,2: [2][NN][NN]
                  const void* __restrict__ theta,           // [3][F][32], dtype per flag
                  unsigned short* __restrict__ X,           // out [bt*32+o][NN] bf16
                  const int* __restrict__ flagp){
  constexpr int MT  = MTILE/16;
  constexpr int Kp  = (F == 16) ? 64 : 96;    // zero-padded K for the mix MFMA
  constexpr int PP  = (F == 16) ? 72 : 104;   // LDS pitch (16B-multiple, bank-spread)
  constexpr int G   = MTILE / F;              // bt-groups per tile
  constexpr int NKB = Kp / 32;
  constexpr int BUF = MTILE*32 + 2*128*32;    // halves per buffer (A | B)

  __shared__ __align__(16) unsigned short SMEM[2*BUF];     // dbuf, reused as zs
  __shared__ __align__(16) unsigned short TT[32*PP];       // theta^T bf16 [o][kk]

  int flag = *flagp;
  int tid  = threadIdx.x;
  int w    = tid >> 6, lane = tid & 63, q = lane >> 4, cc = lane & 15;
  int row0 = blockIdx.x * MTILE;
  int gn0  = blockIdx.y * 128;

  // stage theta^T (zero-padded)
  for (int idx = tid; idx < 32*PP; idx += 256){
    int o = idx / PP, kk = idx % PP;
    float v = (kk < 3*F) ? ld(theta, (size_t)kk*32 + o, flag) : 0.f;
    TT[idx] = f2b(v);
  }

  unsigned short* A0 = SMEM;
  unsigned short* B0 = SMEM + MTILE*32;
  unsigned short* A1 = SMEM + BUF;
  unsigned short* B1 = SMEM + BUF + MTILE*32;

  f32x4 zero4 = {0.f, 0.f, 0.f, 0.f};
  f32x4 acc[2][MT][2];
  #pragma unroll
  for (int k = 0; k < 2; ++k)
    #pragma unroll
    for (int mt = 0; mt < MT; ++mt)
      #pragma unroll
      for (int ns = 0; ns < 2; ++ns) acc[k][mt][ns] = zero4;

  // prologue: fill buffer 0 (also covers the TT stores via the barrier)
  stage_tile<MTILE>(Ag, chb, A0, B0, row0, gn0, 0, tid);
  __syncthreads();

  // 64 K-steps of 32; prefetch next strip before computing current
  for (int it = 0; it < 62; it += 2){
    stage_tile<MTILE>(Ag, chb, A1, B1, row0, gn0, (it+1)*32, tid);
    compute_tile<MT>(A0, B0, acc, w, cc, q);
    __syncthreads();                    // vmcnt(0)+lgkmcnt(0)+barrier: next buf ready
    stage_tile<MTILE>(Ag, chb, A0, B0, row0, gn0, (it+2)*32, tid);
    compute_tile<MT>(A1, B1, acc, w, cc, q);
    __syncthreads();
  }
  stage_tile<MTILE>(Ag, chb, A1, B1, row0, gn0, 63*32, tid);
  compute_tile<MT>(A0, B0, acc, w, cc, q);
  __syncthreads();
  compute_tile<MT>(A1, B1, acc, w, cc, q);
  __syncthreads();   // main-loop LDS reads done; SMEM free for reuse; TT visible

  // ---- epilogue: wave-private z repack + theta^T MFMA mix ----
  unsigned short* zs = SMEM + w * (32*PP);   // [32 cols][PP]

  short8 afm[2][NKB];
  #pragma unroll
  for (int mt_o = 0; mt_o < 2; ++mt_o)
    #pragma unroll
    for (int kb = 0; kb < NKB; ++kb)
      afm[mt_o][kb] = *(const short8*)(TT + (mt_o*16 + cc)*PP + kb*32 + q*8);

  if (F == 16){                              // zero rows [48,64) once
    if (lane < 32){
      #pragma unroll
      for (int j = 0; j < 4; ++j) *(uint2*)(zs + lane*PP + 48 + j*4) = make_uint2(0u, 0u);
    }
  }

  int bt0 = row0 / F;
  #pragma unroll
  for (int g = 0; g < G; ++g){
    float sc = SCALE ? att[bt0 + g] : 1.f;
    // identity rows [0,F): zs[col][f] = Ag[row0+g*F+f][gn0 + w*32 + col] (scaled)
    #pragma unroll
    for (int pass = 0; pass < F/16; ++pass){
      int rf = pass*16 + (lane >> 2), c8 = (lane & 3) * 8;
      uint4 u = *(const uint4*)(Ag + (size_t)(row0 + g*F + rf)*NN + gn0 + w*32 + c8);
      unsigned short sp[8]; __builtin_memcpy(sp, &u, 16);
      #pragma unroll
      for (int e = 0; e < 8; ++e){
        unsigned short val = SCALE ? f2b(b2f(sp[e]) * sc) : sp[e];
        zs[(c8 + e)*PP + rf] = val;
      }
    }
    // plane rows [F,3F) from acc (att scale applied here — commutes with graph mix)
    #pragma unroll
    for (int k = 0; k < 2; ++k)
      #pragma unroll
      for (int mt_l = 0; mt_l < F/16; ++mt_l)
        #pragma unroll
        for (int ns = 0; ns < 2; ++ns){
          int mt = g*(F/16) + mt_l;
          f32x4 v = acc[k][mt][ns];
          #pragma unroll
          for (int r = 0; r < 4; ++r){
            float pv = SCALE ? v[r] * sc : v[r];
            zs[(ns*16 + cc)*PP + F*(k+1) + mt_l*16 + q*4 + r] = f2b(pv);
          }
        }
    // mix MFMA: out[o][col] = sum_kk TT[o][kk] * zs[col][kk]
    #pragma unroll
    for (int mt_o = 0; mt_o < 2; ++mt_o)
      #pragma unroll
      for (int ch = 0; ch < 2; ++ch){
        f32x4 am = zero4;
        #pragma unroll
        for (int kb = 0; kb < NKB; ++kb){
          short8 bm = *(const short8*)(zs + (ch*16 + cc)*PP + kb*32 + q*8);
          am = __builtin_amdgcn_mfma_f32_16x16x32_bf16(afm[mt_o][kb], bm, am, 0, 0, 0);
        }
        #pragma unroll
        for (int r = 0; r < 4; ++r){
          int o = mt_o*16 + q*4 + r;
          float v = am[r]; v = v > 0.f ? v : 0.f;
          X[((size_t)((bt0 + g)*32 + o))*NN + gn0 + w*32 + ch*16 + cc] = f2b(v);
        }
      }
  }
}

// Distinct symbols so rocprof rows are unambiguous (both showed as "k_gemm" before).
// gconv1: MTILE=96 -> grid 64x16 = 1024 blocks = EXACTLY 2 scheduling rounds at
// 2 blocks/CU (was 768 = 1.5 rounds -> 75% utilization in round 2).
__global__ __launch_bounds__(256, 2)
void k_gconv1(const unsigned short* __restrict__ Ag, const float* __restrict__ att,
              const unsigned short* __restrict__ chb, const void* __restrict__ theta,
              unsigned short* __restrict__ X, const int* __restrict__ flagp){
  gemm_body<1, 16, 96>(Ag, att, chb, theta, X, flagp);
}
__global__ __launch_bounds__(256, 2)
void k_gconv2(const unsigned short* __restrict__ Ag, const float* __restrict__ att,
              const unsigned short* __restrict__ chb, const void* __restrict__ theta,
              unsigned short* __restrict__ X, const int* __restrict__ flagp){
  gemm_body<0, 32, 128>(Ag, att, chb, theta, X, flagp);
}

// ---------------- temporal conv 1 (kernel (1,2), wrap-pad, relu) ----------------
__global__ void k_tconv1(const unsigned short* __restrict__ xin,
                         const void* __restrict__ wgt, const void* __restrict__ bias,
                         unsigned short* __restrict__ yout, const int* __restrict__ flagp){
  int flag = *flagp;
  __shared__ float wl[32*32*2];
  __shared__ float bl[32];
  int tid = threadIdx.x;
  for (int i = tid; i < 2048; i += 256) wl[i] = ld(wgt, i, flag);
  if (tid < 32) bl[tid] = ld(bias, tid, flag);
  __syncthreads();
  int bt = blockIdx.x, b = bt / 12, t = bt % 12;
  int c = (t == 0) ? 10 : (t - 1);
  int n = blockIdx.y*256 + tid;
  const unsigned short* p0 = xin + ((size_t)(b*12 + c  )*32)*NN + n;
  const unsigned short* p1 = xin + ((size_t)(b*12 + c+1)*32)*NN + n;
  float acc[32];
  #pragma unroll
  for (int o = 0; o < 32; ++o) acc[o] = bl[o];
  for (int i = 0; i < 32; ++i){
    float v0 = b2f(p0[(size_t)i*NN]);
    float v1 = b2f(p1[(size_t)i*NN]);
    #pragma unroll
    for (int o = 0; o < 32; ++o) acc[o] += v0*wl[o*64 + i*2] + v1*wl[o*64 + i*2 + 1];
  }
  unsigned short* op = yout + ((size_t)bt*32)*NN + n;
  #pragma unroll
  for (int o = 0; o < 32; ++o){ float v = acc[o]; op[(size_t)o*NN] = f2b(v > 0.f ? v : 0.f); }
}

// ---------------- tconv2 + relu + residual + LayerNorm + relu ----------------
// og=2 (16 out-channels per block): halves the redundant re-read of the yp/x slices.
// SPILL DISCIPLINE (rounds 4+5 lesson): acc[16][8] = 128 f32/thread REQUIRES
// __launch_bounds__(256,2); weight reads are scalar LDS broadcasts (wave-uniform).
__global__ __launch_bounds__(256, 2)
void k_tail(const unsigned short* __restrict__ yp,
            const void* __restrict__ x,
            const void* __restrict__ w2, const void* __restrict__ b2v,
            const void* __restrict__ rw, const void* __restrict__ rbv,
            const void* __restrict__ lng, const void* __restrict__ lnb,
            void* __restrict__ out, const int* __restrict__ flagp){
  int flag = *flagp;
  __shared__ float wt0[32*16], wt1[32*16];   // [i][oo] taps, transposed
  __shared__ float rt[16*16];                // [i][oo] residual 1x1, transposed
  __shared__ float bcv[16], rbc[16];
  __shared__ float redS[4*16], redS2[4*16];
  int tid = threadIdx.x;
  int bt = blockIdx.x, og = blockIdx.y, o0 = og*16;
  int b = bt / 12, t = bt % 12, c = (t == 0) ? 10 : (t - 1);
  for (int idx = tid; idx < 512; idx += 256){
    int i = idx >> 4, oo = idx & 15;
    wt0[idx] = ld(w2, (size_t)(o0 + oo)*64 + i*2,     flag);
    wt1[idx] = ld(w2, (size_t)(o0 + oo)*64 + i*2 + 1, flag);
  }
  if (tid < 256){
    int i = tid >> 4, oo = tid & 15;
    rt[tid] = ld(rw, (size_t)(o0 + oo)*16 + i, flag);
  }
  if (tid < 16){ bcv[tid] = ld(b2v, o0 + tid, flag); rbc[tid] = ld(rbv, o0 + tid, flag); }
  __syncthreads();
  float acc[16][8];
  #pragma unroll
  for (int oo = 0; oo < 16; ++oo)
    #pragma unroll
    for (int nn = 0; nn < 8; ++nn) acc[oo][nn] = bcv[oo];
  const unsigned short* p0 = yp + ((size_t)(b*12 + c  )*32)*NN;
  const unsigned short* p1 = yp + ((size_t)(b*12 + c+1)*32)*NN;
  for (int i = 0; i < 32; ++i){
    float v0[8], v1[8];
    #pragma unroll
    for (int nn = 0; nn < 8; ++nn){
      int n = nn*256 + tid;
      v0[nn] = b2f(p0[(size_t)i*NN + n]);
      v1[nn] = b2f(p1[(size_t)i*NN + n]);
    }
    #pragma unroll
    for (int oo = 0; oo < 16; ++oo){
      float w0 = wt0[i*16 + oo];
      float w1 = wt1[i*16 + oo];
      #pragma unroll
      for (int nn = 0; nn < 8; ++nn) acc[oo][nn] += v0[nn]*w0 + v1[nn]*w1;
    }
  }
  #pragma unroll
  for (int oo = 0; oo < 16; ++oo)
    #pragma unroll
    for (int nn = 0; nn < 8; ++nn){ float v = acc[oo][nn]; acc[oo][nn] = (v > 0.f ? v : 0.f) + rbc[oo]; }
  size_t xbase = ((size_t)(b*12 + t)*16)*NN;
  for (int i = 0; i < 16; ++i){
    float xv[8];
    #pragma unroll
    for (int nn = 0; nn < 8; ++nn) xv[nn] = ld(x, xbase + (size_t)i*NN + nn*256 + tid, flag);
    #pragma unroll
    for (int oo = 0; oo < 16; ++oo){
      float r = rt[i*16 + oo];
      #pragma unroll
      for (int nn = 0; nn < 8; ++nn) acc[oo][nn] += xv[nn]*r;
    }
  }
  int lane = tid & 63, wv = tid >> 6;
  #pragma unroll
  for (int oo = 0; oo < 16; ++oo){
    float s = 0.f, s2 = 0.f;
    #pragma unroll
    for (int nn = 0; nn < 8; ++nn){ float v = acc[oo][nn]; s += v; s2 += v*v; }
    for (int off = 32; off; off >>= 1){ s += __shfl_down(s, off); s2 += __shfl_down(s2, off); }
    if (lane == 0){ redS[wv*16 + oo] = s; redS2[wv*16 + oo] = s2; }
  }
  __syncthreads();
  size_t obase = ((size_t)((b*12 + t)*32 + o0))*NN;
  #pragma unroll
  for (int nn = 0; nn < 8; ++nn){
    int n = nn*256 + tid;
    float g = ld(lng, n, flag), be = ld(lnb, n, flag);
    #pragma unroll
    for (int oo = 0; oo < 16; ++oo){
      float S  = redS [oo] + redS [16 + oo] + redS [32 + oo] + redS [48 + oo];
      float S2 = redS2[oo] + redS2[16 + oo] + redS2[32 + oo] + redS2[48 + oo];
      float m = S * (1.f/2048.f);
      float var = S2 * (1.f/2048.f) - m*m;
      float inv = rsqrtf(var + 1e-5f);
      float v = (acc[oo][nn] - m)*inv*g + be;
      v = v > 0.f ? v : 0.f;
      if (flag) ((unsigned short*)out)[obase + (size_t)oo*NN + n] = f2b(v);
      else      ((float*)out)[obase + (size_t)oo*NN + n] = v;
    }
  }
}

// ---------------- launcher ----------------
extern "C" void kernel_launch(void* const* d_in, const int* in_sizes, int n_in,
                              void* d_out, int out_size, void* d_ws, size_t ws_size,
                              hipStream_t stream){
  const void* x    = d_in[0];
  const void* cheb = d_in[1];
  const void* th1  = d_in[2];
  const void* th2  = d_in[3];
  const void* m1w  = d_in[4];
  const void* m1b  = d_in[5];
  const void* m2w  = d_in[6];
  const void* m2b  = d_in[7];
  const void* t1w  = d_in[8];
  const void* t1b  = d_in[9];
  const void* t2w  = d_in[10];
  const void* t2b  = d_in[11];
  const void* rw   = d_in[12];
  const void* rb   = d_in[13];
  const void* lng  = d_in[14];
  const void* lnb  = d_in[15];
  char* ws = (char*)d_ws;

  int*   flag  = (int*)ws;
  float* att0  = (float*)(ws + 4096);
  float* att   = (float*)(ws + 8192);
  unsigned short* xb  = (unsigned short*)(ws + 16384);        // x bf16: 25.2 MB
  unsigned short* chb = xb + (size_t)M1*NN;                   // cheb planes 1,2 bf16: 16.8 MB
  unsigned short* X1  = chb + (size_t)2*NN*NN;                // gconv1 out: 50.3 MB
  unsigned short* X2  = (unsigned short*)d_out;               // gconv2 out (bf16 scratch in d_out)
  unsigned short* Y1  = X1;                                   // tconv1 out reuses X1

  k_sniff  <<<1, 64, 0, stream>>>((const unsigned short*)x, flag, att0);
  k_convert<<<((long long)M1*NN/8 + 255)/256, 256, 0, stream>>>(x, xb, (long long)M1*NN/8, flag, 0, att0);
  k_convert<<<((long long)2*NN*NN/8 + 255)/256, 256, 0, stream>>>(cheb, chb, (long long)2*NN*NN/8, flag, (long long)NN*NN, nullptr);
  k_att_mlp <<<1, 64, 0, stream>>>(att0, m1w, m1b, m2w, m2b, att, flag);

  k_gconv1<<<dim3(M1/96, 16), 256, 0, stream>>>(xb, att, chb, th1, X1, flag);
  k_gconv2<<<dim3(M2/128, 16), 256, 0, stream>>>(X1, att, chb, th2, X2, flag);

  k_tconv1<<<dim3(384, 8), 256, 0, stream>>>(X2, t1w, t1b, Y1, flag);
  k_tail  <<<dim3(384, 2), 256, 0, stream>>>(Y1, x, t2w, t2b, rw, rb, lng, lnb, d_out, flag);
}

// Round 9
// 741.729 us; speedup vs baseline: 1.0495x; 1.0003x over previous
//
#include <hip/hip_runtime.h>

#define DI __device__ __forceinline__

typedef __attribute__((ext_vector_type(8))) short short8;   // 8 bf16 (round-4-verified MFMA frag type)
typedef __attribute__((ext_vector_type(4))) float f32x4;

static constexpr int Bb  = 32;
static constexpr int Tt  = 12;
static constexpr int FIN = 16;
static constexpr int NN  = 2048;
static constexpr int HID = 3;
static constexpr int M1  = Bb*Tt*FIN;    // 6144
static constexpr int M2  = Bb*Tt*32;     // 12288

DI float b2f(unsigned short u){
  unsigned int v = ((unsigned int)u) << 16;
  float f; __builtin_memcpy(&f, &v, 4); return f;
}
DI unsigned short f2b(float f){
  unsigned int v; __builtin_memcpy(&v, &f, 4);
  v = v + 0x7FFFu + ((v >> 16) & 1u);
  return (unsigned short)(v >> 16);
}
DI float ld(const void* p, size_t i, int flag){
  return flag ? b2f(((const unsigned short*)p)[i]) : ((const float*)p)[i];
}

// async global->LDS, 16B per lane. LDS dest must be wave-uniform base + lane*16 (it is:
// dest offsets are tid-linear). Global src is per-lane (carries the XOR swizzle).
typedef __attribute__((address_space(1))) const unsigned int g_u32;
typedef __attribute__((address_space(3))) unsigned int l_u32;
DI void gll16(const unsigned short* g, unsigned short* l){
  __builtin_amdgcn_global_load_lds((g_u32*)g, (l_u32*)l, 16, 0, 0);
}

// inline dtype sniff from x[0..127] bytes: wave-0 ballot, broadcast via LDS.
// Every block computes the same result from the same (L2-hot) data.
DI int sniff_flag(const unsigned short* x, int tid, int* flagS){
  if (tid < 64){
    float v = b2f(x[tid*2]);
    int bad = (!(v == v)) || (fabsf(v) > 1e6f);
    unsigned long long m = __ballot(bad);
    if (tid == 0) *flagS = (m == 0ull) ? 1 : 0;
  }
  __syncthreads();
  return *flagS;
}

// ---------------- merged convert (x + cheb planes 1,2) with inline sniff + att-mean ----
// blocks [0, NBX): x -> xb (bf16), accumulate per-(b,t) sums into att0 (atomicAdd).
// blocks [NBX, NBX+NBC): cheb plane 1,2 -> chb.
// block 0 publishes flag for downstream kernels.
static constexpr int NBX = (M1*NN/8)/256;      // 6144
static constexpr int NBC = (2*NN*NN/8)/256;    // 4096
__global__ void k_convert(const void* __restrict__ xsrc, const void* __restrict__ csrc,
                          unsigned short* __restrict__ xb, unsigned short* __restrict__ chb,
                          float* __restrict__ att0, int* __restrict__ flagp){
  __shared__ int flagS;
  __shared__ float red[4];
  int tid = threadIdx.x;
  int flag = sniff_flag((const unsigned short*)xsrc, tid, &flagS);
  if (blockIdx.x == 0 && tid == 0) *flagp = flag;

  if ((int)blockIdx.x < NBX){
    long long i = (long long)blockIdx.x*256 + tid;
    size_t base = (size_t)i * 8;
    float s = 0.f;
    if (flag){
      uint4 u = *(const uint4*)((const unsigned short*)xsrc + base);
      *(uint4*)(xb + base) = u;
      unsigned short sp[8]; __builtin_memcpy(sp, &u, 16);
      #pragma unroll
      for (int j = 0; j < 8; ++j) s += b2f(sp[j]);
    } else {
      const float* f = (const float*)xsrc + base;
      unsigned short o[8];
      #pragma unroll
      for (int j = 0; j < 8; ++j){ float fv = f[j]; o[j] = f2b(fv); s += fv; }
      uint4 ov; __builtin_memcpy(&ov, o, 16);
      *(uint4*)(xb + base) = ov;
    }
    for (int o2 = 32; o2; o2 >>= 1) s += __shfl_down(s, o2);
    if ((tid & 63) == 0) red[tid >> 6] = s;
    __syncthreads();
    if (tid == 0){
      int bt = (int)(blockIdx.x >> 4);   // 2048 elems/block, 32768 elems per (b,t)
      atomicAdd(&att0[bt], red[0] + red[1] + red[2] + red[3]);
    }
  } else {
    long long i = (long long)((int)blockIdx.x - NBX)*256 + tid;
    size_t base = (size_t)i * 8;
    size_t off  = (size_t)NN*NN;         // skip identity plane
    if (flag){
      *(uint4*)(chb + base) = *(const uint4*)((const unsigned short*)csrc + off + base);
    } else {
      const float* f = (const float*)csrc + off + base;
      unsigned short o[8];
      #pragma unroll
      for (int j = 0; j < 8; ++j) o[j] = f2b(f[j]);
      uint4 ov; __builtin_memcpy(&ov, o, 16);
      *(uint4*)(chb + base) = ov;
    }
  }
}

// ---------------- fused gconv main-loop helpers ----------------
// stage one BK=32 K-strip of A[MTILE][32] + B[2][128][32] into LDS buffer (async,
// swizzled src). Guard for MTILE<128 is safe: sync is via __syncthreads (full drain).
template <int MTILE>
DI void stage_tile(const unsigned short* __restrict__ Ag,
                   const unsigned short* __restrict__ chb,
                   unsigned short* Ad, unsigned short* Bd,
                   int row0, int gn0, int kk0, int tid){
  #pragma unroll
  for (int p = 0; p < 2; ++p){
    int s = tid + p*256;
    if (s < MTILE*4){
      int r = s >> 2, j = s & 3;       // A: MTILE rows x 4 blocks of 8 bf16
      gll16(Ag + (size_t)(row0 + r)*NN + kk0 + ((j ^ (r & 3)) << 3), Ad + (s << 3));
    }
  }
  #pragma unroll
  for (int p = 0; p < 4; ++p){
    int s = tid + p*256, k = s >> 9, rem = s & 511, r = rem >> 2, j = rem & 3;  // B: 2 planes
    gll16(chb + (size_t)k*NN*NN + (size_t)(gn0 + r)*NN + kk0 + ((j ^ (r & 3)) << 3), Bd + (s << 3));
  }
}

// consume one staged BK=32 strip: (MT+4) ds_read_b128 + 4*MT MFMA
template <int MT>
DI void compute_tile(const unsigned short* As, const unsigned short* Bs,
                     f32x4 (&acc)[2][MT][2], int w, int cc, int q){
  short8 af[MT];
  #pragma unroll
  for (int mt = 0; mt < MT; ++mt)
    af[mt] = *(const short8*)(As + ((mt*16 + cc) << 5) + ((q ^ (cc & 3)) << 3));
  #pragma unroll
  for (int k = 0; k < 2; ++k){
    #pragma unroll
    for (int ns = 0; ns < 2; ++ns){
      int r = w*32 + ns*16 + cc;       // (r&3) == (cc&3)
      short8 bv = *(const short8*)(Bs + (((k << 7) + r) << 5) + ((q ^ (cc & 3)) << 3));
      #pragma unroll
      for (int mt = 0; mt < MT; ++mt)
        acc[k][mt][ns] = __builtin_amdgcn_mfma_f32_16x16x32_bf16(af[mt], bv, acc[k][mt][ns], 0, 0, 0);
    }
  }
}

// ---------------- fused gconv body: X[bt*32+o][n] = relu( sum_kk theta_T[o][kk]*z[kk][n] )
// zfull rows: [0,F) identity (A, att-scaled if SCALE), [F,2F) A@cheb1^T, [2F,3F) A@cheb2^T.
// Main loop: MTILE x 128 tile MFMA GEMM over 2 cheb planes, BK=32, LDS double-buffered,
// staged via global_load_lds (16B), next-tile prefetch issued before compute.
// PIPELINE VERDICT (rounds 2,3,7): counted-vmcnt rings are null-to-negative on this
// 2-phase structure; the plain __syncthreads dbuf IS the m97 ceiling (873 TF measured).
// XCD remap (FETCH 2.6x) and occupancy raises (acc spill) also refuted. 2 blocks/CU is
// register-mandated (acc 128 AGPR + 128 VGPR = the full 256/wave budget at 2 waves/SIMD).
// If SCALE: the SE-attention MLP is computed INLINE (first G threads) from att0 raw sums
// — k_att_mlp launch eliminated.
template <int SCALE, int F, int MTILE>
DI void gemm_body(const unsigned short* __restrict__ Ag,
                  const unsigned short* __restrict__ chb,   // planes 1,2: [2][NN][NN]
                  const void* __restrict__ theta,           // [3][F][32], dtype per flag
                  unsigned short* __restrict__ X,           // out [bt*32+o][NN] bf16
                  const int* __restrict__ flagp,
                  const float* __restrict__ att0,
                  const void* __restrict__ m1w, const void* __restrict__ m1b,
                  const void* __restrict__ m2w, const void* __restrict__ m2b){
  constexpr int MT  = MTILE/16;
  constexpr int Kp  = (F == 16) ? 64 : 96;    // zero-padded K for the mix MFMA
  constexpr int PP  = (F == 16) ? 72 : 104;   // LDS pitch (16B-multiple, bank-spread)
  constexpr int G   = MTILE / F;              // bt-groups per tile
  constexpr int NKB = Kp / 32;
  constexpr int BUF = MTILE*32 + 2*128*32;    // halves per buffer (A | B)

  __shared__ __align__(16) unsigned short SMEM[2*BUF];     // dbuf, reused as zs
  __shared__ __align__(16) unsigned short TT[32*PP];       // theta^T bf16 [o][kk]
  __shared__ float attS[G > 0 ? G : 1];

  int flag = *flagp;
  int tid  = threadIdx.x;
  int w    = tid >> 6, lane = tid & 63, q = lane >> 4, cc = lane & 15;
  int row0 = blockIdx.x * MTILE;
  int gn0  = blockIdx.y * 128;
  int bt0  = row0 / F;

  // stage theta^T (zero-padded)
  for (int idx = tid; idx < 32*PP; idx += 256){
    int o = idx / PP, kk = idx % PP;
    float v = (kk < 3*F) ? ld(theta, (size_t)kk*32 + o, flag) : 0.f;
    TT[idx] = f2b(v);
  }
  // inline SE-attention MLP for this block's G bt-groups (trivial: ~100 FLOP/thread)
  if (SCALE && tid < G){
    int bt = bt0 + tid, bb = bt / Tt, tt = bt % Tt;
    float a[Tt];
    #pragma unroll
    for (int t2 = 0; t2 < Tt; ++t2) a[t2] = att0[bb*Tt + t2] * (1.f / (FIN*NN));
    float h[HID];
    #pragma unroll
    for (int j = 0; j < HID; ++j){
      float s = ld(m1b, j, flag);
      #pragma unroll
      for (int t2 = 0; t2 < Tt; ++t2) s += a[t2] * ld(m1w, j*Tt + t2, flag);
      h[j] = s > 0.f ? s : 0.f;
    }
    float s = ld(m2b, tt, flag);
    #pragma unroll
    for (int j = 0; j < HID; ++j) s += h[j] * ld(m2w, tt*HID + j, flag);
    attS[tid] = 1.f / (1.f + expf(-s));
  }

  unsigned short* A0 = SMEM;
  unsigned short* B0 = SMEM + MTILE*32;
  unsigned short* A1 = SMEM + BUF;
  unsigned short* B1 = SMEM + BUF + MTILE*32;

  f32x4 zero4 = {0.f, 0.f, 0.f, 0.f};
  f32x4 acc[2][MT][2];
  #pragma unroll
  for (int k = 0; k < 2; ++k)
    #pragma unroll
    for (int mt = 0; mt < MT; ++mt)
      #pragma unroll
      for (int ns = 0; ns < 2; ++ns) acc[k][mt][ns] = zero4;

  // prologue: fill buffer 0 (barrier also covers TT + attS stores)
  stage_tile<MTILE>(Ag, chb, A0, B0, row0, gn0, 0, tid);
  __syncthreads();

  // 64 K-steps of 32; prefetch next strip before computing current
  for (int it = 0; it < 62; it += 2){
    stage_tile<MTILE>(Ag, chb, A1, B1, row0, gn0, (it+1)*32, tid);
    compute_tile<MT>(A0, B0, acc, w, cc, q);
    __syncthreads();                    // vmcnt(0)+lgkmcnt(0)+barrier: next buf ready
    stage_tile<MTILE>(Ag, chb, A0, B0, row0, gn0, (it+2)*32, tid);
    compute_tile<MT>(A1, B1, acc, w, cc, q);
    __syncthreads();
  }
  stage_tile<MTILE>(Ag, chb, A1, B1, row0, gn0, 63*32, tid);
  compute_tile<MT>(A0, B0, acc, w, cc, q);
  __syncthreads();
  compute_tile<MT>(A1, B1, acc, w, cc, q);
  __syncthreads();   // main-loop LDS reads done; SMEM free for reuse; TT/attS visible

  // ---- epilogue: wave-private z repack + theta^T MFMA mix ----
  unsigned short* zs = SMEM + w * (32*PP);   // [32 cols][PP]

  short8 afm[2][NKB];
  #pragma unroll
  for (int mt_o = 0; mt_o < 2; ++mt_o)
    #pragma unroll
    for (int kb = 0; kb < NKB; ++kb)
      afm[mt_o][kb] = *(const short8*)(TT + (mt_o*16 + cc)*PP + kb*32 + q*8);

  if (F == 16){                              // zero rows [48,64) once
    if (lane < 32){
      #pragma unroll
      for (int j = 0; j < 4; ++j) *(uint2*)(zs + lane*PP + 48 + j*4) = make_uint2(0u, 0u);
    }
  }

  #pragma unroll
  for (int g = 0; g < G; ++g){
    float sc = SCALE ? attS[g] : 1.f;
    // identity rows [0,F): zs[col][f] = Ag[row0+g*F+f][gn0 + w*32 + col] (scaled)
    #pragma unroll
    for (int pass = 0; pass < F/16; ++pass){
      int rf = pass*16 + (lane >> 2), c8 = (lane & 3) * 8;
      uint4 u = *(const uint4*)(Ag + (size_t)(row0 + g*F + rf)*NN + gn0 + w*32 + c8);
      unsigned short sp[8]; __builtin_memcpy(sp, &u, 16);
      #pragma unroll
      for (int e = 0; e < 8; ++e){
        unsigned short val = SCALE ? f2b(b2f(sp[e]) * sc) : sp[e];
        zs[(c8 + e)*PP + rf] = val;
      }
    }
    // plane rows [F,3F) from acc (att scale applied here — commutes with graph mix)
    #pragma unroll
    for (int k = 0; k < 2; ++k)
      #pragma unroll
      for (int mt_l = 0; mt_l < F/16; ++mt_l)
        #pragma unroll
        for (int ns = 0; ns < 2; ++ns){
          int mt = g*(F/16) + mt_l;
          f32x4 v = acc[k][mt][ns];
          #pragma unroll
          for (int r = 0; r < 4; ++r){
            float pv = SCALE ? v[r] * sc : v[r];
            zs[(ns*16 + cc)*PP + F*(k+1) + mt_l*16 + q*4 + r] = f2b(pv);
          }
        }
    // mix MFMA: out[o][col] = sum_kk TT[o][kk] * zs[col][kk]
    #pragma unroll
    for (int mt_o = 0; mt_o < 2; ++mt_o)
      #pragma unroll
      for (int ch = 0; ch < 2; ++ch){
        f32x4 am = zero4;
        #pragma unroll
        for (int kb = 0; kb < NKB; ++kb){
          short8 bm = *(const short8*)(zs + (ch*16 + cc)*PP + kb*32 + q*8);
          am = __builtin_amdgcn_mfma_f32_16x16x32_bf16(afm[mt_o][kb], bm, am, 0, 0, 0);
        }
        #pragma unroll
        for (int r = 0; r < 4; ++r){
          int o = mt_o*16 + q*4 + r;
          float v = am[r]; v = v > 0.f ? v : 0.f;
          X[((size_t)((bt0 + g)*32 + o))*NN + gn0 + w*32 + ch*16 + cc] = f2b(v);
        }
      }
  }
}

// Distinct symbols so rocprof rows are unambiguous.
// gconv1: MTILE=96 -> 1024 blocks = exactly 2 scheduling rounds at 2 blocks/CU.
__global__ __launch_bounds__(256, 2)
void k_gconv1(const unsigned short* __restrict__ Ag, const unsigned short* __restrict__ chb,
              const void* __restrict__ theta, unsigned short* __restrict__ X,
              const int* __restrict__ flagp, const float* __restrict__ att0,
              const void* __restrict__ m1w, const void* __restrict__ m1b,
              const void* __restrict__ m2w, const void* __restrict__ m2b){
  gemm_body<1, 16, 96>(Ag, chb, theta, X, flagp, att0, m1w, m1b, m2w, m2b);
}
__global__ __launch_bounds__(256, 2)
void k_gconv2(const unsigned short* __restrict__ Ag, const unsigned short* __restrict__ chb,
              const void* __restrict__ theta, unsigned short* __restrict__ X,
              const int* __restrict__ flagp){
  gemm_body<0, 32, 128>(Ag, chb, theta, X, flagp, nullptr, nullptr, nullptr, nullptr, nullptr);
}

// ---------------- temporal conv 1 (kernel (1,2), wrap-pad, relu) ----------------
__global__ void k_tconv1(const unsigned short* __restrict__ xin,
                         const void* __restrict__ wgt, const void* __restrict__ bias,
                         unsigned short* __restrict__ yout, const int* __restrict__ flagp){
  int flag = *flagp;
  __shared__ float wl[32*32*2];
  __shared__ float bl[32];
  int tid = threadIdx.x;
  for (int i = tid; i < 2048; i += 256) wl[i] = ld(wgt, i, flag);
  if (tid < 32) bl[tid] = ld(bias, tid, flag);
  __syncthreads();
  int bt = blockIdx.x, b = bt / 12, t = bt % 12;
  int c = (t == 0) ? 10 : (t - 1);
  int n = blockIdx.y*256 + tid;
  const unsigned short* p0 = xin + ((size_t)(b*12 + c  )*32)*NN + n;
  const unsigned short* p1 = xin + ((size_t)(b*12 + c+1)*32)*NN + n;
  float acc[32];
  #pragma unroll
  for (int o = 0; o < 32; ++o) acc[o] = bl[o];
  for (int i = 0; i < 32; ++i){
    float v0 = b2f(p0[(size_t)i*NN]);
    float v1 = b2f(p1[(size_t)i*NN]);
    #pragma unroll
    for (int o = 0; o < 32; ++o) acc[o] += v0*wl[o*64 + i*2] + v1*wl[o*64 + i*2 + 1];
  }
  unsigned short* op = yout + ((size_t)bt*32)*NN + n;
  #pragma unroll
  for (int o = 0; o < 32; ++o){ float v = acc[o]; op[(size_t)o*NN] = f2b(v > 0.f ? v : 0.f); }
}

// ---------------- tconv2 + relu + residual + LayerNorm + relu ----------------
// og=2 (16 out-channels per block): halves the redundant re-read of the yp/x slices.
// SPILL DISCIPLINE (rounds 4+5 lesson): acc[16][8] = 128 f32/thread REQUIRES
// __launch_bounds__(256,2); weight reads are scalar LDS broadcasts (wave-uniform).
__global__ __launch_bounds__(256, 2)
void k_tail(const unsigned short* __restrict__ yp,
            const void* __restrict__ x,
            const void* __restrict__ w2, const void* __restrict__ b2v,
            const void* __restrict__ rw, const void* __restrict__ rbv,
            const void* __restrict__ lng, const void* __restrict__ lnb,
            void* __restrict__ out, const int* __restrict__ flagp){
  int flag = *flagp;
  __shared__ float wt0[32*16], wt1[32*16];   // [i][oo] taps, transposed
  __shared__ float rt[16*16];                // [i][oo] residual 1x1, transposed
  __shared__ float bcv[16], rbc[16];
  __shared__ float redS[4*16], redS2[4*16];
  int tid = threadIdx.x;
  int bt = blockIdx.x, og = blockIdx.y, o0 = og*16;
  int b = bt / 12, t = bt % 12, c = (t == 0) ? 10 : (t - 1);
  for (int idx = tid; idx < 512; idx += 256){
    int i = idx >> 4, oo = idx & 15;
    wt0[idx] = ld(w2, (size_t)(o0 + oo)*64 + i*2,     flag);
    wt1[idx] = ld(w2, (size_t)(o0 + oo)*64 + i*2 + 1, flag);
  }
  if (tid < 256){
    int i = tid >> 4, oo = tid & 15;
    rt[tid] = ld(rw, (size_t)(o0 + oo)*16 + i, flag);
  }
  if (tid < 16){ bcv[tid] = ld(b2v, o0 + tid, flag); rbc[tid] = ld(rbv, o0 + tid, flag); }
  __syncthreads();
  float acc[16][8];
  #pragma unroll
  for (int oo = 0; oo < 16; ++oo)
    #pragma unroll
    for (int nn = 0; nn < 8; ++nn) acc[oo][nn] = bcv[oo];
  const unsigned short* p0 = yp + ((size_t)(b*12 + c  )*32)*NN;
  const unsigned short* p1 = yp + ((size_t)(b*12 + c+1)*32)*NN;
  for (int i = 0; i < 32; ++i){
    float v0[8], v1[8];
    #pragma unroll
    for (int nn = 0; nn < 8; ++nn){
      int n = nn*256 + tid;
      v0[nn] = b2f(p0[(size_t)i*NN + n]);
      v1[nn] = b2f(p1[(size_t)i*NN + n]);
    }
    #pragma unroll
    for (int oo = 0; oo < 16; ++oo){
      float w0 = wt0[i*16 + oo];
      float w1 = wt1[i*16 + oo];
      #pragma unroll
      for (int nn = 0; nn < 8; ++nn) acc[oo][nn] += v0[nn]*w0 + v1[nn]*w1;
    }
  }
  #pragma unroll
  for (int oo = 0; oo < 16; ++oo)
    #pragma unroll
    for (int nn = 0; nn < 8; ++nn){ float v = acc[oo][nn]; acc[oo][nn] = (v > 0.f ? v : 0.f) + rbc[oo]; }
  size_t xbase = ((size_t)(b*12 + t)*16)*NN;
  for (int i = 0; i < 16; ++i){
    float xv[8];
    #pragma unroll
    for (int nn = 0; nn < 8; ++nn) xv[nn] = ld(x, xbase + (size_t)i*NN + nn*256 + tid, flag);
    #pragma unroll
    for (int oo = 0; oo < 16; ++oo){
      float r = rt[i*16 + oo];
      #pragma unroll
      for (int nn = 0; nn < 8; ++nn) acc[oo][nn] += xv[nn]*r;
    }
  }
  int lane = tid & 63, wv = tid >> 6;
  #pragma unroll
  for (int oo = 0; oo < 16; ++oo){
    float s = 0.f, s2 = 0.f;
    #pragma unroll
    for (int nn = 0; nn < 8; ++nn){ float v = acc[oo][nn]; s += v; s2 += v*v; }
    for (int off = 32; off; off >>= 1){ s += __shfl_down(s, off); s2 += __shfl_down(s2, off); }
    if (lane == 0){ redS[wv*16 + oo] = s; redS2[wv*16 + oo] = s2; }
  }
  __syncthreads();
  size_t obase = ((size_t)((b*12 + t)*32 + o0))*NN;
  #pragma unroll
  for (int nn = 0; nn < 8; ++nn){
    int n = nn*256 + tid;
    float g = ld(lng, n, flag), be = ld(lnb, n, flag);
    #pragma unroll
    for (int oo = 0; oo < 16; ++oo){
      float S  = redS [oo] + redS [16 + oo] + redS [32 + oo] + redS [48 + oo];
      float S2 = redS2[oo] + redS2[16 + oo] + redS2[32 + oo] + redS2[48 + oo];
      float m = S * (1.f/2048.f);
      float var = S2 * (1.f/2048.f) - m*m;
      float inv = rsqrtf(var + 1e-5f);
      float v = (acc[oo][nn] - m)*inv*g + be;
      v = v > 0.f ? v : 0.f;
      if (flag) ((unsigned short*)out)[obase + (size_t)oo*NN + n] = f2b(v);
      else      ((float*)out)[obase + (size_t)oo*NN + n] = v;
    }
  }
}

// ---------------- launcher (5 launches, was 8) ----------------
extern "C" void kernel_launch(void* const* d_in, const int* in_sizes, int n_in,
                              void* d_out, int out_size, void* d_ws, size_t ws_size,
                              hipStream_t stream){
  const void* x    = d_in[0];
  const void* cheb = d_in[1];
  const void* th1  = d_in[2];
  const void* th2  = d_in[3];
  const void* m1w  = d_in[4];
  const void* m1b  = d_in[5];
  const void* m2w  = d_in[6];
  const void* m2b  = d_in[7];
  const void* t1w  = d_in[8];
  const void* t1b  = d_in[9];
  const void* t2w  = d_in[10];
  const void* t2b  = d_in[11];
  const void* rw   = d_in[12];
  const void* rb   = d_in[13];
  const void* lng  = d_in[14];
  const void* lnb  = d_in[15];
  char* ws = (char*)d_ws;

  int*   flag  = (int*)ws;
  float* att0  = (float*)(ws + 4096);
  unsigned short* xb  = (unsigned short*)(ws + 16384);        // x bf16: 25.2 MB
  unsigned short* chb = xb + (size_t)M1*NN;                   // cheb planes 1,2 bf16: 16.8 MB
  unsigned short* X1  = chb + (size_t)2*NN*NN;                // gconv1 out: 50.3 MB
  unsigned short* X2  = (unsigned short*)d_out;               // gconv2 out (bf16 scratch in d_out)
  unsigned short* Y1  = X1;                                   // tconv1 out reuses X1

  hipMemsetAsync(att0, 0, Bb*Tt*sizeof(float), stream);       // graph-capture-safe
  k_convert<<<NBX + NBC, 256, 0, stream>>>(x, cheb, xb, chb, att0, flag);

  k_gconv1<<<dim3(M1/96, 16), 256, 0, stream>>>(xb, chb, th1, X1, flag, att0, m1w, m1b, m2w, m2b);
  k_gconv2<<<dim3(M2/128, 16), 256, 0, stream>>>(X1, chb, th2, X2, flag);

  k_tconv1<<<dim3(384, 8), 256, 0, stream>>>(X2, t1w, t1b, Y1, flag);
  k_tail  <<<dim3(384, 2), 256, 0, stream>>>(Y1, x, t2w, t2b, rw, rb, lng, lnb, d_out, flag);
}